// Round 2
// baseline (7564.608 us; speedup 1.0000x reference)
//
#include <hip/hip_runtime.h>
#include <hip/hip_bf16.h>

// LSTM T=4096, B=16, I=64, H=256 (4H=1024 gate rows), O=1.
//
// Round-2 design:
//  - Kernel A: precompute x_gates[t][b][j] = x@W_ih^T + b_ih + b_hh into d_ws
//    as fp16 (128 MB). Massively parallel, ~tens of us.
//  - Kernel B: 16 WGs (one per batch) x 512 threads. Thread tid owns gate
//    rows r0=tid (i|f half) and r1=tid+512 (g|o half) -> all 1024 rows.
//    W_hh fp16: 116 f16x2 pairs/row in VGPRs (232 regs) + 12 pairs/row in
//    LDS (48 KB, transposed for conflict-free reads). h as f16x2 in LDS
//    (broadcast reads). fp32 accumulators, fp32 cell state in-thread.
//    2 barriers/step. VALU floor ~1024 cyc/step.

typedef _Float16 f16x2 __attribute__((ext_vector_type(2)));
typedef _Float16 f16x8 __attribute__((ext_vector_type(8)));

#define T_STEPS 4096
#define BATCH   16
#define IN      64
#define HID     256
#define G4      1024
#define NPAIR   128      // 256 k-values as f16x2 pairs
#define REG_PAIRS 116    // pairs per row held in VGPRs
#define LDS_PAIRS 12     // pairs per row held in LDS (116+12 = 128)
#define NCHUNK   29      // REG_PAIRS / 4 (f16x8 h-chunks)

__device__ __forceinline__ float fdot2(f16x2 a, f16x2 b, float c) {
#if __has_builtin(__builtin_amdgcn_fdot2)
    return __builtin_amdgcn_fdot2(a, b, c, false);
#else
    return c + (float)a.x * (float)b.x + (float)a.y * (float)b.y;
#endif
}

__device__ __forceinline__ float sigf(float x) {
    return 1.0f / (1.0f + __expf(-x));
}
__device__ __forceinline__ float tanh_fast(float x) {
    return 2.0f * sigf(2.0f * x) - 1.0f;
}

// ---------------- Kernel A: x_gates precompute ----------------
__global__ __launch_bounds__(256) void xg_precompute(
    const float* __restrict__ x, const float* __restrict__ W_ih,
    const float* __restrict__ b_ih, const float* __restrict__ b_hh,
    _Float16* __restrict__ xg)
{
    const int b   = blockIdx.x;
    const int t0  = blockIdx.y * 128;
    const int tid = threadIdx.x;

    __shared__ __align__(16) f16x2 xs2[IN / 2];

    // Thread owns rows {tid, tid+256, tid+512, tid+768}: W_ih fp16 in regs.
    f16x2 wih[4][32];
    float bias[4];
    const float2* W2 = (const float2*)W_ih;
    #pragma unroll
    for (int g = 0; g < 4; ++g) {
        const int r = tid + g * 256;
        #pragma unroll
        for (int m = 0; m < 32; ++m) {
            float2 v = W2[r * 32 + m];
            wih[g][m] = f16x2{(_Float16)v.x, (_Float16)v.y};
        }
        bias[g] = b_ih[r] + b_hh[r];
    }

    for (int tt = 0; tt < 128; ++tt) {
        const int t = t0 + tt;
        if (tid < 32) {
            float2 v = ((const float2*)x)[(t * BATCH + b) * 32 + tid];
            xs2[tid] = f16x2{(_Float16)v.x, (_Float16)v.y};
        }
        __syncthreads();
        float acc[4] = {bias[0], bias[1], bias[2], bias[3]};
        #pragma unroll
        for (int m = 0; m < 32; ++m) {
            f16x2 xv = xs2[m];
            #pragma unroll
            for (int g = 0; g < 4; ++g) acc[g] = fdot2(wih[g][m], xv, acc[g]);
        }
        #pragma unroll
        for (int g = 0; g < 4; ++g)
            xg[(t * BATCH + b) * G4 + g * 256 + tid] = (_Float16)acc[g];
        __syncthreads();
    }
}

// ---------------- Kernel B: persistent recurrence ----------------
template <bool PRE>
__global__ __launch_bounds__(512) void lstm_rec(
    const float* __restrict__ x,     const float* __restrict__ W_ih,
    const float* __restrict__ W_hh,  const float* __restrict__ b_ih,
    const float* __restrict__ b_hh,  const float* __restrict__ W_lin,
    const float* __restrict__ b_lin, const float* __restrict__ h0,
    const float* __restrict__ c0,    const _Float16* __restrict__ xg,
    float* __restrict__ out)
{
    const int b   = blockIdx.x;
    const int tid = threadIdx.x;
    const int r0  = tid;        // rows 0..511   (i-gate | f-gate)
    const int r1  = tid + 512;  // rows 512..1023 (g-gate | o-gate)

    __shared__ __align__(16) f16x2 wt[LDS_PAIRS * 1024];  // 48 KB, [m][row]
    __shared__ __align__(16) f16x2 hsh2[NPAIR];           // h fp16 pairs
    __shared__ float fsh[256];
    __shared__ float osh[256];
    __shared__ float xsf[IN];                             // non-PRE staging

    // ---- one-time: W_hh -> fp16 regs + LDS tail ----
    f16x2 w0[REG_PAIRS], w1[REG_PAIRS];
    const float2* Wh2 = (const float2*)W_hh;
    #pragma unroll
    for (int p = 0; p < REG_PAIRS; ++p) {
        float2 v = Wh2[r0 * 128 + p];
        w0[p] = f16x2{(_Float16)v.x, (_Float16)v.y};
        v = Wh2[r1 * 128 + p];
        w1[p] = f16x2{(_Float16)v.x, (_Float16)v.y};
    }
    #pragma unroll
    for (int m = 0; m < LDS_PAIRS; ++m) {
        float2 v = Wh2[r0 * 128 + REG_PAIRS + m];
        wt[m * 1024 + r0] = f16x2{(_Float16)v.x, (_Float16)v.y};
        v = Wh2[r1 * 128 + REG_PAIRS + m];
        wt[m * 1024 + r1] = f16x2{(_Float16)v.x, (_Float16)v.y};
    }

    float bias0 = 0.0f, bias1 = 0.0f;
    if (!PRE) { bias0 = b_ih[r0] + b_hh[r0]; bias1 = b_ih[r1] + b_hh[r1]; }

    // ---- state ----
    float c = 0.0f, hval = 0.0f, gi = 0.0f, gg = 0.0f;
    _Float16* hsh_h = (_Float16*)hsh2;
    if (tid < HID) {
        c    = c0[b * HID + tid];
        hval = h0[b * HID + tid];
        hsh_h[tid] = (_Float16)hval;
    }

    float xg0c = 0.0f, xg1c = 0.0f, xnext = 0.0f;
    if (PRE) {
        xg0c = (float)xg[b * G4 + r0];
        xg1c = (float)xg[b * G4 + r1];
    } else {
        if (tid < IN) xnext = x[b * IN + tid];
    }

    const f16x8* h8 = (const f16x8*)hsh2;

    for (int t = 0; t < T_STEPS; ++t) {
        __syncthreads();  // B1: h(t), wt visible

        float acc0, acc1;
        float xg0n = 0.0f, xg1n = 0.0f;
        if (PRE) {
            if (t + 1 < T_STEPS) {  // prefetch next step's x-gates (HBM hidden)
                xg0n = (float)xg[((t + 1) * BATCH + b) * G4 + r0];
                xg1n = (float)xg[((t + 1) * BATCH + b) * G4 + r1];
            }
            acc0 = xg0c; acc1 = xg1c;
        } else {
            __asm__ volatile("" ::: "memory");  // defeat W_ih load hoisting
            if (tid < IN) xsf[tid] = xnext;
            __syncthreads();  // B1b
            if (tid < IN && t + 1 < T_STEPS)
                xnext = x[((t + 1) * BATCH + b) * IN + tid];
            acc0 = bias0; acc1 = bias1;
            const float4* W4 = (const float4*)W_ih;
            #pragma unroll
            for (int ic = 0; ic < 16; ++ic) {
                float4 wv = W4[r0 * 16 + ic];
                acc0 += wv.x * xsf[ic*4] + wv.y * xsf[ic*4+1]
                      + wv.z * xsf[ic*4+2] + wv.w * xsf[ic*4+3];
                wv = W4[r1 * 16 + ic];
                acc1 += wv.x * xsf[ic*4] + wv.y * xsf[ic*4+1]
                      + wv.z * xsf[ic*4+2] + wv.w * xsf[ic*4+3];
            }
        }

        // ---- h . W_hh : 116 reg-pairs via f16x8 broadcast chunks ----
        #pragma unroll
        for (int cc = 0; cc < NCHUNK; ++cc) {
            union { f16x8 v; f16x2 p[4]; } hu;
            hu.v = h8[cc];
            #pragma unroll
            for (int u = 0; u < 4; ++u) {
                acc0 = fdot2(w0[cc * 4 + u], hu.p[u], acc0);
                acc1 = fdot2(w1[cc * 4 + u], hu.p[u], acc1);
            }
        }
        // ---- 12 LDS tail pairs ----
        #pragma unroll
        for (int m = 0; m < LDS_PAIRS; ++m) {
            f16x2 hp = hsh2[REG_PAIRS + m];
            acc0 = fdot2(wt[m * 1024 + r0], hp, acc0);
            acc1 = fdot2(wt[m * 1024 + r1], hp, acc1);
        }

        // ---- activations (wave-uniform split) ----
        float a0 = sigf(acc0);                    // i (tid<256) or f (else)
        if (tid < 256) {
            gi = a0;
            gg = tanh_fast(acc1);                 // g
        } else {
            fsh[tid - 256] = a0;                  // f for unit tid-256
            osh[tid - 256] = sigf(acc1);          // o for unit tid-256
        }
        __syncthreads();  // B2: gates ready

        if (tid < 256) {
            c    = fsh[tid] * c + gi * gg;
            hval = osh[tid] * tanh_fast(c);
            hsh_h[tid] = (_Float16)hval;          // h(t+1)
        }
        if (PRE) { xg0c = xg0n; xg1c = xg1n; }
    }

    // ---- epilogue: y[b] = sigmoid(h . W_lin + b_lin) ----
    if (tid < 256) fsh[tid] = hval * W_lin[tid];
    __syncthreads();
    if (tid == 0) {
        float z = b_lin[0];
        for (int n = 0; n < 256; ++n) z += fsh[n];
        out[b] = sigf(z);
    }
}

extern "C" void kernel_launch(void* const* d_in, const int* in_sizes, int n_in,
                              void* d_out, int out_size, void* d_ws, size_t ws_size,
                              hipStream_t stream) {
    const float* x     = (const float*)d_in[0];
    const float* W_ih  = (const float*)d_in[1];
    const float* W_hh  = (const float*)d_in[2];
    const float* b_ih  = (const float*)d_in[3];
    const float* b_hh  = (const float*)d_in[4];
    const float* W_lin = (const float*)d_in[5];
    const float* b_lin = (const float*)d_in[6];
    const float* h0    = (const float*)d_in[7];
    const float* c0    = (const float*)d_in[8];
    float* out = (float*)d_out;

    const size_t need = (size_t)T_STEPS * BATCH * G4 * sizeof(_Float16); // 128 MB
    if (ws_size >= need) {
        _Float16* xg = (_Float16*)d_ws;
        xg_precompute<<<dim3(BATCH, 32), 256, 0, stream>>>(x, W_ih, b_ih, b_hh, xg);
        lstm_rec<true><<<dim3(BATCH), 512, 0, stream>>>(
            x, W_ih, W_hh, b_ih, b_hh, W_lin, b_lin, h0, c0, xg, out);
    } else {
        lstm_rec<false><<<dim3(BATCH), 512, 0, stream>>>(
            x, W_ih, W_hh, b_ih, b_hh, W_lin, b_lin, h0, c0,
            (const _Float16*)nullptr, out);
    }
}

// Round 3
// 7531.987 us; speedup vs baseline: 1.0043x; 1.0043x over previous
//
#include <hip/hip_runtime.h>
#include <hip/hip_bf16.h>

// LSTM T=4096, B=16, I=64, H=256 (4H=1024 gate rows), O=1.
//
// R3: same structure as R2 (16 WGs x 512 thr, thread owns rows tid and
// tid+512; W_hh fp16: 116 f16x2 pairs in VGPRs + 12 pairs in LDS), with:
//  - __launch_bounds__(512, 2): 2 waves/SIMD -> 256-VGPR tier. R2's missing
//    min-waves arg capped VGPRs at 128 and spilled the weight registers to
//    scratch every step (VGPR_Count=128 in rocprof; 4330 cyc/step vs 1024
//    dot2 floor).
//  - LDS weight tail repacked as f16x8 (ds_read_b128 x6 instead of
//    ds_read_b32 x24 per thread-step).

typedef _Float16 f16x2 __attribute__((ext_vector_type(2)));
typedef _Float16 f16x8 __attribute__((ext_vector_type(8)));

#define T_STEPS 4096
#define BATCH   16
#define IN      64
#define HID     256
#define G4      1024
#define REG_PAIRS 116    // f16x2 pairs per row in VGPRs (29 f16x8 chunks)
#define NCHUNK    29     // REG_PAIRS / 4
#define TAILCH    3      // LDS tail: 3 f16x8 chunks = 12 pairs (116+12=128)

__device__ __forceinline__ float fdot2(f16x2 a, f16x2 b, float c) {
#if __has_builtin(__builtin_amdgcn_fdot2)
    return __builtin_amdgcn_fdot2(a, b, c, false);
#else
    return c + (float)a.x * (float)b.x + (float)a.y * (float)b.y;
#endif
}

__device__ __forceinline__ float sigf(float x) {
    return 1.0f / (1.0f + __expf(-x));
}
__device__ __forceinline__ float tanh_fast(float x) {
    return 2.0f * sigf(2.0f * x) - 1.0f;
}

// ---------------- Kernel A: x_gates precompute ----------------
__global__ __launch_bounds__(256) void xg_precompute(
    const float* __restrict__ x, const float* __restrict__ W_ih,
    const float* __restrict__ b_ih, const float* __restrict__ b_hh,
    _Float16* __restrict__ xg)
{
    const int b   = blockIdx.x;
    const int t0  = blockIdx.y * 128;
    const int tid = threadIdx.x;

    __shared__ __align__(16) f16x2 xs2[IN / 2];

    f16x2 wih[4][32];
    float bias[4];
    const float2* W2 = (const float2*)W_ih;
    #pragma unroll
    for (int g = 0; g < 4; ++g) {
        const int r = tid + g * 256;
        #pragma unroll
        for (int m = 0; m < 32; ++m) {
            float2 v = W2[r * 32 + m];
            wih[g][m] = f16x2{(_Float16)v.x, (_Float16)v.y};
        }
        bias[g] = b_ih[r] + b_hh[r];
    }

    for (int tt = 0; tt < 128; ++tt) {
        const int t = t0 + tt;
        if (tid < 32) {
            float2 v = ((const float2*)x)[(t * BATCH + b) * 32 + tid];
            xs2[tid] = f16x2{(_Float16)v.x, (_Float16)v.y};
        }
        __syncthreads();
        float acc[4] = {bias[0], bias[1], bias[2], bias[3]};
        #pragma unroll
        for (int m = 0; m < 32; ++m) {
            f16x2 xv = xs2[m];
            #pragma unroll
            for (int g = 0; g < 4; ++g) acc[g] = fdot2(wih[g][m], xv, acc[g]);
        }
        #pragma unroll
        for (int g = 0; g < 4; ++g)
            xg[(t * BATCH + b) * G4 + g * 256 + tid] = (_Float16)acc[g];
        __syncthreads();
    }
}

// ---------------- Kernel B: persistent recurrence ----------------
template <bool PRE>
__global__ __launch_bounds__(512, 2) void lstm_rec(
    const float* __restrict__ x,     const float* __restrict__ W_ih,
    const float* __restrict__ W_hh,  const float* __restrict__ b_ih,
    const float* __restrict__ b_hh,  const float* __restrict__ W_lin,
    const float* __restrict__ b_lin, const float* __restrict__ h0,
    const float* __restrict__ c0,    const _Float16* __restrict__ xg,
    float* __restrict__ out)
{
    const int b   = blockIdx.x;
    const int tid = threadIdx.x;
    const int r0  = tid;        // rows 0..511    (i | f)
    const int r1  = tid + 512;  // rows 512..1023 (g | o)

    // LDS: tail weights as f16x8 [chunk][row] (48 KB) + h + gate staging.
    __shared__ __align__(16) f16x8 wt8[TAILCH * 1024];   // 49152 B
    __shared__ __align__(16) f16x8 hsh8[32];             // h as 32 f16x8 = 512 B
    __shared__ float fsh[256];
    __shared__ float osh[256];
    __shared__ float xsf[IN];

    // ---- one-time: W_hh -> fp16 regs + LDS tail ----
    f16x2 w0[REG_PAIRS], w1[REG_PAIRS];
    const float2* Wh2 = (const float2*)W_hh;
    #pragma unroll
    for (int p = 0; p < REG_PAIRS; ++p) {
        float2 v = Wh2[r0 * 128 + p];
        w0[p] = f16x2{(_Float16)v.x, (_Float16)v.y};
        v = Wh2[r1 * 128 + p];
        w1[p] = f16x2{(_Float16)v.x, (_Float16)v.y};
    }
    #pragma unroll
    for (int tc = 0; tc < TAILCH; ++tc) {
        union { f16x8 v; f16x2 p[4]; } ua, ub;
        #pragma unroll
        for (int u = 0; u < 4; ++u) {
            float2 v = Wh2[r0 * 128 + REG_PAIRS + tc * 4 + u];
            ua.p[u] = f16x2{(_Float16)v.x, (_Float16)v.y};
            v = Wh2[r1 * 128 + REG_PAIRS + tc * 4 + u];
            ub.p[u] = f16x2{(_Float16)v.x, (_Float16)v.y};
        }
        wt8[tc * 1024 + r0] = ua.v;
        wt8[tc * 1024 + r1] = ub.v;
    }

    float bias0 = 0.0f, bias1 = 0.0f;
    if (!PRE) { bias0 = b_ih[r0] + b_hh[r0]; bias1 = b_ih[r1] + b_hh[r1]; }

    // ---- state ----
    float c = 0.0f, hval = 0.0f, gi = 0.0f, gg = 0.0f;
    _Float16* hsh_h = (_Float16*)hsh8;
    if (tid < HID) {
        c    = c0[b * HID + tid];
        hval = h0[b * HID + tid];
        hsh_h[tid] = (_Float16)hval;
    }

    float xg0c = 0.0f, xg1c = 0.0f, xnext = 0.0f;
    if (PRE) {
        xg0c = (float)xg[b * G4 + r0];
        xg1c = (float)xg[b * G4 + r1];
    } else {
        if (tid < IN) xnext = x[b * IN + tid];
    }

    for (int t = 0; t < T_STEPS; ++t) {
        __syncthreads();  // B1: h(t) visible

        float acc0, acc1;
        float xg0n = 0.0f, xg1n = 0.0f;
        if (PRE) {
            if (t + 1 < T_STEPS) {  // prefetch next step's x-gates
                xg0n = (float)xg[((t + 1) * BATCH + b) * G4 + r0];
                xg1n = (float)xg[((t + 1) * BATCH + b) * G4 + r1];
            }
            acc0 = xg0c; acc1 = xg1c;
        } else {
            __asm__ volatile("" ::: "memory");
            if (tid < IN) xsf[tid] = xnext;
            __syncthreads();
            if (tid < IN && t + 1 < T_STEPS)
                xnext = x[((t + 1) * BATCH + b) * IN + tid];
            acc0 = bias0; acc1 = bias1;
            const float4* W4 = (const float4*)W_ih;
            #pragma unroll
            for (int ic = 0; ic < 16; ++ic) {
                float4 wv = W4[r0 * 16 + ic];
                acc0 += wv.x * xsf[ic*4] + wv.y * xsf[ic*4+1]
                      + wv.z * xsf[ic*4+2] + wv.w * xsf[ic*4+3];
                wv = W4[r1 * 16 + ic];
                acc1 += wv.x * xsf[ic*4] + wv.y * xsf[ic*4+1]
                      + wv.z * xsf[ic*4+2] + wv.w * xsf[ic*4+3];
            }
        }

        // ---- h . W_hh : 29 register chunks (b128 broadcast h) ----
        #pragma unroll
        for (int cc = 0; cc < NCHUNK; ++cc) {
            union { f16x8 v; f16x2 p[4]; } hu;
            hu.v = hsh8[cc];
            #pragma unroll
            for (int u = 0; u < 4; ++u) {
                acc0 = fdot2(w0[cc * 4 + u], hu.p[u], acc0);
                acc1 = fdot2(w1[cc * 4 + u], hu.p[u], acc1);
            }
        }
        // ---- 3 LDS tail chunks (b128 weight reads) ----
        #pragma unroll
        for (int tc = 0; tc < TAILCH; ++tc) {
            union { f16x8 v; f16x2 p[4]; } hu, wa, wb;
            hu.v = hsh8[NCHUNK + tc];
            wa.v = wt8[tc * 1024 + r0];
            wb.v = wt8[tc * 1024 + r1];
            #pragma unroll
            for (int u = 0; u < 4; ++u) {
                acc0 = fdot2(wa.p[u], hu.p[u], acc0);
                acc1 = fdot2(wb.p[u], hu.p[u], acc1);
            }
        }

        // ---- activations ----
        float a0 = sigf(acc0);                    // i (tid<256) or f
        if (tid < 256) {
            gi = a0;
            gg = tanh_fast(acc1);                 // g
        } else {
            fsh[tid - 256] = a0;                  // f
            osh[tid - 256] = sigf(acc1);          // o
        }
        __syncthreads();  // B2: gates ready

        if (tid < 256) {
            c    = fsh[tid] * c + gi * gg;
            hval = osh[tid] * tanh_fast(c);
            hsh_h[tid] = (_Float16)hval;          // h(t+1)
        }
        if (PRE) { xg0c = xg0n; xg1c = xg1n; }
    }

    // ---- epilogue: y[b] = sigmoid(h . W_lin + b_lin) ----
    if (tid < 256) fsh[tid] = hval * W_lin[tid];
    __syncthreads();
    if (tid == 0) {
        float z = b_lin[0];
        for (int n = 0; n < 256; ++n) z += fsh[n];
        out[b] = sigf(z);
    }
}

extern "C" void kernel_launch(void* const* d_in, const int* in_sizes, int n_in,
                              void* d_out, int out_size, void* d_ws, size_t ws_size,
                              hipStream_t stream) {
    const float* x     = (const float*)d_in[0];
    const float* W_ih  = (const float*)d_in[1];
    const float* W_hh  = (const float*)d_in[2];
    const float* b_ih  = (const float*)d_in[3];
    const float* b_hh  = (const float*)d_in[4];
    const float* W_lin = (const float*)d_in[5];
    const float* b_lin = (const float*)d_in[6];
    const float* h0    = (const float*)d_in[7];
    const float* c0    = (const float*)d_in[8];
    float* out = (float*)d_out;

    const size_t need = (size_t)T_STEPS * BATCH * G4 * sizeof(_Float16); // 128 MB
    if (ws_size >= need) {
        _Float16* xg = (_Float16*)d_ws;
        xg_precompute<<<dim3(BATCH, 32), 256, 0, stream>>>(x, W_ih, b_ih, b_hh, xg);
        lstm_rec<true><<<dim3(BATCH), 512, 0, stream>>>(
            x, W_ih, W_hh, b_ih, b_hh, W_lin, b_lin, h0, c0, xg, out);
    } else {
        lstm_rec<false><<<dim3(BATCH), 512, 0, stream>>>(
            x, W_ih, W_hh, b_ih, b_hh, W_lin, b_lin, h0, c0,
            (const _Float16*)nullptr, out);
    }
}